// Round 13
// baseline (158.839 us; speedup 1.0000x reference)
//
#include <hip/hip_runtime.h>
#include <hip/hip_bf16.h>
#include <cstdint>

// Problem constants: B=4, C=feat=64, N=H*W=4096.
#define BB 4
#define CC 64
#define NN 4096
#define NWRD 64          // 4096 bits / 64 per mask row
#define TAU 0.005f
#define EPSN 1e-5f
#define MSPLITS 16

typedef __attribute__((ext_vector_type(8))) short short8;   // 8 bf16 (4 VGPRs)
typedef __attribute__((ext_vector_type(4))) float f32x4;
typedef unsigned long long ull;

__device__ inline unsigned int bf16_rne(float v) {
    unsigned int u = __float_as_uint(v);
    return (u + 0x7FFFu + ((u >> 16) & 1u)) >> 16;
}

// async 16B global->LDS copy: LDS dest = wave-uniform base + lane*16 [m97/m104]
__device__ inline void gload_lds16(const void* g, void* lds_base) {
    __builtin_amdgcn_global_load_lds(
        (const __attribute__((address_space(1))) unsigned int*)g,
        (__attribute__((address_space(3))) unsigned int*)lds_base, 16, 0, 0);
}

// ---------------- K1: LDS-tiled transpose -> xt fp32 + normalized bf16 hi/lo; zero deg
__global__ __launch_bounds__(256) void k_transpose(const float* __restrict__ x,
                                                   float* __restrict__ xt,
                                                   unsigned short* __restrict__ ynh,
                                                   unsigned short* __restrict__ ynl,
                                                   int* __restrict__ deg) {
    __shared__ float lds[64 * 65];
    int t = threadIdx.x;
    int b = blockIdx.y;
    int n0 = blockIdx.x * 64;
    int gid = (b * (NN / 64) + blockIdx.x) * 256 + t;
    if (gid < BB * NN) deg[gid] = 0;          // zero for k_corr's atomics
    #pragma unroll
    for (int i = 0; i < 4; ++i) {
        int c = i * 16 + (t >> 4);
        int nc = (t & 15) * 4;
        float4 v = *(const float4*)(x + ((size_t)(b * CC + c)) * NN + n0 + nc);
        lds[c * 65 + nc + 0] = v.x;
        lds[c * 65 + nc + 1] = v.y;
        lds[c * 65 + nc + 2] = v.z;
        lds[c * 65 + nc + 3] = v.w;
    }
    __syncthreads();
    int l = t & 63, wv = t >> 6;
    for (int i = 0; i < 16; ++i) {
        int n = wv * 16 + i;
        float v = lds[l * 65 + n];
        float s = v * v;
        #pragma unroll
        for (int off = 32; off; off >>= 1) s += __shfl_xor(s, off, 64);
        float yv = v * rsqrtf(s);
        unsigned int hb = bf16_rne(yv);
        float lo = yv - __uint_as_float(hb << 16);
        unsigned int lb = bf16_rne(lo);
        size_t row = (size_t)(b * NN + n0 + n);
        xt[row * CC + l] = v;
        ynh[row * CC + l] = (unsigned short)hb;
        ynl[row * CC + l] = (unsigned short)lb;
    }
}

// ---------------- K2: MFMA correlation, async dbuf staging, 4 blocks/CU ---------
// Block: 4 waves x 64n = 256 n; sweeps 256 m in 4 chunks of 64 (hi+lo, swizzled).
#define CORR_MC 64
__global__ __launch_bounds__(256) void k_corr(const unsigned short* __restrict__ ynh,
                                              const unsigned short* __restrict__ ynl,
                                              ull* __restrict__ mask,
                                              int* __restrict__ deg) {
    __shared__ unsigned short ldsH[2][CORR_MC * 64];   // 2 x 8 KB
    __shared__ unsigned short ldsL[2][CORR_MC * 64];   // 2 x 8 KB
    int t = threadIdx.x;
    int l = t & 63, wv = t >> 6;
    int lc = l & 15, q = l >> 4;
    int b = blockIdx.z;
    int n0 = blockIdx.x * 256 + wv * 64;
    int m0 = blockIdx.y * 256;
    const unsigned short* bH = ynh + (size_t)b * NN * CC;
    const unsigned short* bL = ynl + (size_t)b * NN * CC;

    short8 ah[4][2], al[4][2];
    #pragma unroll
    for (int nt = 0; nt < 4; ++nt)
        #pragma unroll
        for (int ks = 0; ks < 2; ++ks) {
            size_t off = (size_t)(n0 + nt * 16 + lc) * CC + (ks * 4 + q) * 8;
            ah[nt][ks] = *(const short8*)(bH + off);
            al[nt][ks] = *(const short8*)(bL + off);
        }

    int rr = l & 15;
    int rsel = rr & 3;
    int qq = rr >> 2;
    int myq = l >> 4;        // this lane's n-tile (0..3)

    // async stage of 64-m chunk; source index permuted so the HW lane*16 deposit
    // reproduces the xor-swizzled layout.
    auto stage = [&](int mc, int bufi) {
        int mbase = m0 + mc * CORR_MC;
        #pragma unroll
        for (int rd = 0; rd < 2; ++rd) {
            int gu = rd * 256 + wv * 64;               // wave-uniform part
            int g = gu + l;                            // 16B-chunk id 0..511
            int ci = (g & ~7) | ((g & 7) ^ ((g >> 3) & 7));
            gload_lds16(bH + (size_t)mbase * CC + ci * 8, &ldsH[bufi][gu * 8]);
            gload_lds16(bL + (size_t)mbase * CC + ci * 8, &ldsL[bufi][gu * 8]);
        }
    };

    ull wout[4];
    int degacc = 0;
    stage(0, 0);
    for (int mc = 0; mc < 4; ++mc) {
        __syncthreads();
        if (mc + 1 < 4) stage(mc + 1, (mc + 1) & 1);
        int bufi = mc & 1;
        ull w = 0;
        #pragma unroll
        for (int tt = 0; tt < 4; ++tt) {
            short8 bh[2], bl[2];
            #pragma unroll
            for (int ks = 0; ks < 2; ++ks) {
                int rowm = tt * 16 + lc;
                int sw = ((ks * 4 + q) ^ (rowm & 7)) * 8;
                bh[ks] = *(const short8*)&ldsH[bufi][rowm * 64 + sw];
                bl[ks] = *(const short8*)&ldsL[bufi][rowm * 64 + sw];
            }
            #pragma unroll
            for (int nt = 0; nt < 4; ++nt) {
                f32x4 acc = {0.f, 0.f, 0.f, 0.f};
                #pragma unroll
                for (int ks = 0; ks < 2; ++ks) {
                    acc = __builtin_amdgcn_mfma_f32_16x16x32_bf16(ah[nt][ks], bh[ks], acc, 0, 0, 0);
                    acc = __builtin_amdgcn_mfma_f32_16x16x32_bf16(ah[nt][ks], bl[ks], acc, 0, 0, 0);
                    acc = __builtin_amdgcn_mfma_f32_16x16x32_bf16(al[nt][ks], bh[ks], acc, 0, 0, 0);
                }
                ull bal[4];
                #pragma unroll
                for (int r = 0; r < 4; ++r)
                    bal[r] = __ballot(acc[r] > TAU);
                ull sa = (rsel & 1) ? bal[1] : bal[0];
                ull sb = (rsel & 1) ? bal[3] : bal[2];
                ull sel = (rsel & 2) ? sb : sa;
                ull part = ((sel >> (qq * 16)) & 0xFFFFull) << (tt * 16);
                if (myq == nt) w |= part;
            }
        }
        wout[mc] = w;
        degacc += __popcll(w);
    }
    int row = n0 + myq * 16 + rr;
    ull* mdst = mask + ((size_t)(b * NN + row)) * NWRD + (m0 >> 6);
    #pragma unroll
    for (int mc = 0; mc < 4; ++mc) mdst[mc] = wout[mc];
    atomicAdd(&deg[b * NN + row], degacc);
}

// ---------------- K3: pack y = dinv.*xin into MFMA b-frag (k-packed) order, bf16
__global__ __launch_bounds__(256) void k_pack(const float* __restrict__ xin,
                                              const int* __restrict__ deg,
                                              unsigned short* __restrict__ yph) {
    __shared__ float lds[32 * 65];
    int t = threadIdx.x;
    int kt = blockIdx.x;                 // 0..127
    int b = blockIdx.y;
    size_t ibase = (size_t)b * NN * CC + (size_t)kt * 32 * CC;
    #pragma unroll
    for (int i = 0; i < 2; ++i) {
        int f4 = i * 256 + t;
        int m = f4 >> 4;
        float d = rsqrtf((float)deg[b * NN + kt * 32 + m]);
        float4 v = ((const float4*)(xin + ibase))[f4];
        int c = (f4 & 15) * 4;
        lds[m * 65 + c + 0] = v.x * d;
        lds[m * 65 + c + 1] = v.y * d;
        lds[m * 65 + c + 2] = v.z * d;
        lds[m * 65 + c + 3] = v.w * d;
    }
    __syncthreads();
    size_t obase = (size_t)b * NN * CC + (size_t)kt * 2048;
    int kin = t & 31;
    int chi = t >> 5;
    #pragma unroll
    for (int cg = 0; cg < 8; ++cg) {
        int c = cg * 8 + chi;
        yph[obase + c * 32 + kin] = (unsigned short)bf16_rne(lds[kin * 65 + c]);
    }
}

// ---------------- K4: MFMA diffusion GEMM, async dbuf staging, 16-way m-split ---
// Block: 4 waves x 64n = 256 n; sweeps 256 m (one split) in 2 chunks of 128.
#define GMC 128
__global__ __launch_bounds__(256) void k_gemm(const ull* __restrict__ mask,
                                              const unsigned short* __restrict__ yph,
                                              float* __restrict__ plx) {
    __shared__ unsigned short ldsB[2][4 * 2048];   // 2 x 16 KB
    int t = threadIdx.x;
    int l = t & 63, wv = t >> 6;
    int lc = l & 15, q = l >> 4;
    int b = blockIdx.z;
    int ms = blockIdx.y;                  // m-split 0..15
    int n0 = blockIdx.x * 256 + wv * 64;
    int m0 = ms * 256;
    const unsigned short* src = yph + (size_t)b * NN * CC;

    // hoist all mask words for this wave's 256-m sweep (2 chunks x 2 words x 4 nt)
    ull mw[2][4][2];
    #pragma unroll
    for (int nt = 0; nt < 4; ++nt) {
        const ull* mrow = mask + ((size_t)(b * NN + n0 + nt * 16 + lc)) * NWRD + (m0 >> 6);
        #pragma unroll
        for (int mc = 0; mc < 2; ++mc) {
            mw[mc][nt][0] = mrow[mc * 2];
            mw[mc][nt][1] = mrow[mc * 2 + 1];
        }
    }

    f32x4 acc[4][4];
    #pragma unroll
    for (int nt = 0; nt < 4; ++nt)
        #pragma unroll
        for (int tt = 0; tt < 4; ++tt) acc[nt][tt] = f32x4{0.f, 0.f, 0.f, 0.f};

    auto stage = [&](int mc, int bufi) {
        int ktbase = (m0 + mc * GMC) >> 5;
        #pragma unroll
        for (int rd = 0; rd < 4; ++rd) {
            int gu = rd * 256 + wv * 64;              // wave-uniform part
            gload_lds16(src + (size_t)ktbase * 2048 + (gu + l) * 8, &ldsB[bufi][gu * 8]);
        }
    };

    stage(0, 0);
    for (int mc = 0; mc < 2; ++mc) {
        __syncthreads();
        if (mc + 1 < 2) stage(mc + 1, 1);
        int bufi = mc & 1;
        #pragma unroll
        for (int kt = 0; kt < 4; ++kt) {
            int sh = (kt & 1) * 32 + q * 8;
            union { unsigned int u[4]; short8 v; } a[4];
            #pragma unroll
            for (int nt = 0; nt < 4; ++nt) {
                unsigned int bits = (unsigned int)(mw[mc][nt][kt >> 1] >> sh) & 0xFFu;
                #pragma unroll
                for (int j = 0; j < 4; ++j)
                    a[nt].u[j] = ((bits >> (2 * j)) & 1u ? 0x3F80u : 0u)
                               | ((bits >> (2 * j + 1)) & 1u ? 0x3F800000u : 0u);
            }
            #pragma unroll
            for (int tt = 0; tt < 4; ++tt) {
                short8 bf = *(const short8*)&ldsB[bufi][kt * 2048 + (tt * 16 + lc) * 32 + q * 8];
                #pragma unroll
                for (int nt = 0; nt < 4; ++nt)
                    acc[nt][tt] = __builtin_amdgcn_mfma_f32_16x16x32_bf16(a[nt].v, bf, acc[nt][tt], 0, 0, 0);
            }
        }
    }
    #pragma unroll
    for (int nt = 0; nt < 4; ++nt)
        #pragma unroll
        for (int tt = 0; tt < 4; ++tt)
            #pragma unroll
            for (int r = 0; r < 4; ++r) {
                int n = n0 + nt * 16 + q * 4 + r;
                int c = tt * 16 + lc;
                plx[((size_t)((ms * BB + b)) * NN + n) * CC + c] = acc[nt][tt][r];
            }
}

// ---------------- K5: reduce partials, *dinv_n, @W, instance norm, relu ---------
// W column in VGPRs; lxs row via broadcast ds_read_b128.
__global__ __launch_bounds__(256) void k_out(const float* __restrict__ plx,
                                             const int* __restrict__ deg,
                                             const float* __restrict__ W,
                                             float* __restrict__ xout,
                                             unsigned short* __restrict__ xpack) {
    __shared__ float lxs[4][68];
    int lane = threadIdx.x & 63;
    int wave = threadIdx.x >> 6;
    int b = blockIdx.y;
    int n0 = blockIdx.x * 16 + wave * 4;
    float Wreg[64];                     // W[:, lane] — coalesced per c across lanes
    #pragma unroll
    for (int c = 0; c < 64; ++c) Wreg[c] = W[c * 64 + lane];
    for (int tI = 0; tI < 4; ++tI) {
        int n = n0 + tI;
        size_t row = (size_t)(b * NN + n);
        float dRow = rsqrtf((float)deg[row]);
        float lx = 0.f;
        #pragma unroll
        for (int s = 0; s < MSPLITS; ++s)
            lx += plx[((size_t)(s * BB + b) * NN + n) * CC + lane];
        lx *= dRow;
        lxs[wave][lane] = lx;            // same-wave LDS exchange (in-order DS)
        float h = 0.f;
        #pragma unroll
        for (int c4 = 0; c4 < 16; ++c4) {
            float4 s4 = *(const float4*)&lxs[wave][c4 * 4];   // broadcast b128
            h += s4.x * Wreg[c4 * 4 + 0] + s4.y * Wreg[c4 * 4 + 1]
               + s4.z * Wreg[c4 * 4 + 2] + s4.w * Wreg[c4 * 4 + 3];
        }
        float mean = h;
        #pragma unroll
        for (int off = 32; off; off >>= 1) mean += __shfl_xor(mean, off, 64);
        mean *= (1.f / 64.f);
        float dv = h - mean;
        float var = dv * dv;
        #pragma unroll
        for (int off = 32; off; off >>= 1) var += __shfl_xor(var, off, 64);
        var *= (1.f / 64.f);
        float o = dv * rsqrtf(var + EPSN);
        o = o > 0.f ? o : 0.f;
        if (xout)
            xout[row * CC + lane] = o;
        if (xpack)   // next-layer B: bf16(o * dinv_n)
            xpack[(size_t)b * NN * CC + (size_t)(n >> 5) * 2048 + lane * 32 + (n & 31)] =
                (unsigned short)bf16_rne(o * dRow);
    }
}

extern "C" void kernel_launch(void* const* d_in, const int* in_sizes, int n_in,
                              void* d_out, int out_size, void* d_ws, size_t ws_size,
                              hipStream_t stream) {
    const float* x  = (const float*)d_in[0];
    const float* W0 = (const float*)d_in[1];
    const float* W1 = (const float*)d_in[2];
    float* out = (float*)d_out;

    char* ws = (char*)d_ws;
    // Workspace layout (~84.1 MiB total)
    ull* mask = (ull*)(ws);                                           // 8 MiB
    float* xt = (float*)(ws + ((size_t)8 << 20));                     // 4 MiB
    unsigned short* ynh = (unsigned short*)(ws + ((size_t)12 << 20)); // 2 MiB
    unsigned short* ynl = (unsigned short*)(ws + ((size_t)14 << 20)); // 2 MiB
    unsigned short* xp0 = (unsigned short*)(ws + ((size_t)16 << 20)); // 2 MiB
    unsigned short* xp1 = (unsigned short*)(ws + ((size_t)18 << 20)); // 2 MiB
    float* plx = (float*)(ws + ((size_t)20 << 20));                   // 64 MiB
    int* deg = (int*)(ws + ((size_t)84 << 20));                       // 64 KiB

    // Build adjacency (deg zeroed in k_transpose, accumulated in k_corr)
    k_transpose<<<dim3(NN / 64, BB), 256, 0, stream>>>(x, xt, ynh, ynl, deg);
    k_corr<<<dim3(NN / 256, NN / 256, BB), 256, 0, stream>>>(ynh, ynl, mask, deg);

    // Layer 1
    k_pack<<<dim3(128, BB), 256, 0, stream>>>(xt, deg, xp0);
    k_gemm<<<dim3(NN / 256, MSPLITS, BB), 256, 0, stream>>>(mask, xp0, plx);
    k_out<<<dim3(NN / 16, BB), 256, 0, stream>>>(plx, deg, W0, nullptr, xp1);

    // Layer 2
    k_gemm<<<dim3(NN / 256, MSPLITS, BB), 256, 0, stream>>>(mask, xp1, plx);
    k_out<<<dim3(NN / 16, BB), 256, 0, stream>>>(plx, deg, W1, out, nullptr);
}

// Round 14
// 153.058 us; speedup vs baseline: 1.0378x; 1.0378x over previous
//
#include <hip/hip_runtime.h>
#include <hip/hip_bf16.h>
#include <cstdint>

// Problem constants: B=4, C=feat=64, N=H*W=4096.
#define BB 4
#define CC 64
#define NN 4096
#define NWRD 64          // 4096 bits / 64 per mask row
#define TAU 0.005f
#define EPSN 1e-5f
#define MSPLITS 8

typedef __attribute__((ext_vector_type(8))) short short8;   // 8 bf16 (4 VGPRs)
typedef __attribute__((ext_vector_type(4))) float f32x4;
typedef unsigned long long ull;

__device__ inline unsigned int bf16_rne(float v) {
    unsigned int u = __float_as_uint(v);
    return (u + 0x7FFFu + ((u >> 16) & 1u)) >> 16;
}

// async 16B global->LDS copy: LDS dest = wave-uniform base + lane*16 [m97/m104]
__device__ inline void gload_lds16(const void* g, void* lds_base) {
    __builtin_amdgcn_global_load_lds(
        (const __attribute__((address_space(1))) unsigned int*)g,
        (__attribute__((address_space(3))) unsigned int*)lds_base, 16, 0, 0);
}

// ---------------- K1: LDS-tiled transpose -> xt fp32 + normalized bf16 hi/lo; zero deg
__global__ __launch_bounds__(256) void k_transpose(const float* __restrict__ x,
                                                   float* __restrict__ xt,
                                                   unsigned short* __restrict__ ynh,
                                                   unsigned short* __restrict__ ynl,
                                                   int* __restrict__ deg) {
    __shared__ float lds[64 * 65];
    int t = threadIdx.x;
    int b = blockIdx.y;
    int n0 = blockIdx.x * 64;
    int gid = (b * (NN / 64) + blockIdx.x) * 256 + t;
    if (gid < BB * NN) deg[gid] = 0;          // zero for k_corr's atomics
    #pragma unroll
    for (int i = 0; i < 4; ++i) {
        int c = i * 16 + (t >> 4);
        int nc = (t & 15) * 4;
        float4 v = *(const float4*)(x + ((size_t)(b * CC + c)) * NN + n0 + nc);
        lds[c * 65 + nc + 0] = v.x;
        lds[c * 65 + nc + 1] = v.y;
        lds[c * 65 + nc + 2] = v.z;
        lds[c * 65 + nc + 3] = v.w;
    }
    __syncthreads();
    int l = t & 63, wv = t >> 6;
    for (int i = 0; i < 16; ++i) {
        int n = wv * 16 + i;
        float v = lds[l * 65 + n];
        float s = v * v;
        #pragma unroll
        for (int off = 32; off; off >>= 1) s += __shfl_xor(s, off, 64);
        float yv = v * rsqrtf(s);
        unsigned int hb = bf16_rne(yv);
        float lo = yv - __uint_as_float(hb << 16);
        unsigned int lb = bf16_rne(lo);
        size_t row = (size_t)(b * NN + n0 + n);
        xt[row * CC + l] = v;
        ynh[row * CC + l] = (unsigned short)hb;
        ynl[row * CC + l] = (unsigned short)lb;
    }
}

// ---------------- K2: MFMA correlation — TRIANGULAR (G symmetric) ---------------
// Block = pair (I<=J) of 256-row blocks; 4 waves x 64 n; sweeps J's 256 m in 2
// async-dbuf chunks of 128. Mirror tile for J>I via 64x64 bit transpose (LDS reuse).
#define CORR_MC 128
__global__ __launch_bounds__(256) void k_corr(const unsigned short* __restrict__ ynh,
                                              const unsigned short* __restrict__ ynl,
                                              ull* __restrict__ mask,
                                              int* __restrict__ deg) {
    __shared__ unsigned short ldsH[2][CORR_MC * 64];   // 2 x 16 KB
    __shared__ unsigned short ldsL[2][CORR_MC * 64];   // 2 x 16 KB
    int t = threadIdx.x;
    int l = t & 63, wv = t >> 6;
    int lc = l & 15, q = l >> 4;
    int b = blockIdx.z;
    // decode triangular pair index -> (I, J), I<=J, 136 pairs
    int idx = blockIdx.x, I = 0;
    while (idx >= 16 - I) { idx -= 16 - I; ++I; }
    int J = I + idx;
    int n0 = I * 256 + wv * 64;
    int m0 = J * 256;
    const unsigned short* bH = ynh + (size_t)b * NN * CC;
    const unsigned short* bL = ynl + (size_t)b * NN * CC;

    short8 ah[4][2], al[4][2];
    #pragma unroll
    for (int nt = 0; nt < 4; ++nt)
        #pragma unroll
        for (int ks = 0; ks < 2; ++ks) {
            size_t off = (size_t)(n0 + nt * 16 + lc) * CC + (ks * 4 + q) * 8;
            ah[nt][ks] = *(const short8*)(bH + off);
            al[nt][ks] = *(const short8*)(bL + off);
        }

    int rr = l & 15;
    int rsel = rr & 3;
    int qq = rr >> 2;
    int myq = l >> 4;        // this lane's n-tile (0..3); lane l owns row n0+l

    auto stage = [&](int mc, int bufi) {
        int mbase = m0 + mc * CORR_MC;
        #pragma unroll
        for (int rd = 0; rd < 4; ++rd) {
            int gu = rd * 256 + wv * 64;               // wave-uniform part
            int g = gu + l;
            int ci = (g & ~7) | ((g & 7) ^ ((g >> 3) & 7));   // pre-permute for swizzle
            gload_lds16(bH + (size_t)mbase * CC + ci * 8, &ldsH[bufi][gu * 8]);
            gload_lds16(bL + (size_t)mbase * CC + ci * 8, &ldsL[bufi][gu * 8]);
        }
    };

    ull wout[4];
    int degacc = 0;
    stage(0, 0);
    for (int mc = 0; mc < 2; ++mc) {
        __syncthreads();
        if (mc == 0) stage(1, 1);
        int bufi = mc & 1;
        ull w0 = 0, w1 = 0;
        #pragma unroll
        for (int tt = 0; tt < 8; ++tt) {
            short8 bh[2], bl[2];
            #pragma unroll
            for (int ks = 0; ks < 2; ++ks) {
                int rowm = tt * 16 + lc;
                int sw = ((ks * 4 + q) ^ (rowm & 7)) * 8;
                bh[ks] = *(const short8*)&ldsH[bufi][rowm * 64 + sw];
                bl[ks] = *(const short8*)&ldsL[bufi][rowm * 64 + sw];
            }
            #pragma unroll
            for (int nt = 0; nt < 4; ++nt) {
                f32x4 acc = {0.f, 0.f, 0.f, 0.f};
                #pragma unroll
                for (int ks = 0; ks < 2; ++ks) {
                    acc = __builtin_amdgcn_mfma_f32_16x16x32_bf16(ah[nt][ks], bh[ks], acc, 0, 0, 0);
                    acc = __builtin_amdgcn_mfma_f32_16x16x32_bf16(ah[nt][ks], bl[ks], acc, 0, 0, 0);
                    acc = __builtin_amdgcn_mfma_f32_16x16x32_bf16(al[nt][ks], bh[ks], acc, 0, 0, 0);
                }
                ull bal[4];
                #pragma unroll
                for (int r = 0; r < 4; ++r)
                    bal[r] = __ballot(acc[r] > TAU);
                ull sa = (rsel & 1) ? bal[1] : bal[0];
                ull sb = (rsel & 1) ? bal[3] : bal[2];
                ull sel = (rsel & 2) ? sb : sa;
                ull part = ((sel >> (qq * 16)) & 0xFFFFull) << ((tt & 3) * 16);
                if (myq == nt) { if (tt < 4) w0 |= part; else w1 |= part; }
            }
        }
        wout[mc * 2 + 0] = w0;
        wout[mc * 2 + 1] = w1;
        degacc += __popcll(w0) + __popcll(w1);
    }

    // direct tile: rows in I-block, word-cols J*4..J*4+3
    int row = b * NN + n0 + l;
    ull* mdst = mask + (size_t)row * NWRD + J * 4;
    #pragma unroll
    for (int c = 0; c < 4; ++c) mdst[c] = wout[c];
    atomicAdd(&deg[row], degacc);

    if (J > I) {
        // mirror tile: rows in J-block, word-cols I*4..I*4+3, via bit transpose
        __syncthreads();
        ull* sh = (ull*)&ldsH[0][0];         // reuse staging LDS (10 KB needed)
        #pragma unroll
        for (int c = 0; c < 4; ++c) sh[(wv * 64 + l) * 5 + c] = wout[c];
        __syncthreads();
        const ull Mv[6] = {0x00000000FFFFFFFFull, 0x0000FFFF0000FFFFull,
                           0x00FF00FF00FF00FFull, 0x0F0F0F0F0F0F0F0Full,
                           0x3333333333333333ull, 0x5555555555555555ull};
        int dm = 0;
        ull tw[4];
        #pragma unroll
        for (int a = 0; a < 4; ++a) {
            // gather: lane l takes n-row (a*64+l)'s word for m-subblock wv
            ull xv = sh[(a * 64 + l) * 5 + wv];
            int dd = 32;
            #pragma unroll
            for (int s = 0; s < 6; ++s, dd >>= 1) {   // 64x64 bit transpose
                ull y = __shfl_xor(xv, dd, 64);
                ull M = Mv[s];
                xv = (l & dd) ? ((xv & ~M) | ((y >> dd) & M))
                              : ((xv & M) | ((y << dd) & ~M));
            }
            tw[a] = xv;
            dm += __popcll(xv);
        }
        int mrow = b * NN + J * 256 + wv * 64 + l;
        #pragma unroll
        for (int a = 0; a < 4; ++a)
            mask[(size_t)mrow * NWRD + I * 4 + a] = tw[a];
        atomicAdd(&deg[mrow], dm);
    }
}

// ---------------- K3: pack y = dinv.*xin into MFMA b-frag (k-packed) order, bf16
__global__ __launch_bounds__(256) void k_pack(const float* __restrict__ xin,
                                              const int* __restrict__ deg,
                                              unsigned short* __restrict__ yph) {
    __shared__ float lds[32 * 65];
    int t = threadIdx.x;
    int kt = blockIdx.x;                 // 0..127
    int b = blockIdx.y;
    size_t ibase = (size_t)b * NN * CC + (size_t)kt * 32 * CC;
    #pragma unroll
    for (int i = 0; i < 2; ++i) {
        int f4 = i * 256 + t;
        int m = f4 >> 4;
        float d = rsqrtf((float)deg[b * NN + kt * 32 + m]);
        float4 v = ((const float4*)(xin + ibase))[f4];
        int c = (f4 & 15) * 4;
        lds[m * 65 + c + 0] = v.x * d;
        lds[m * 65 + c + 1] = v.y * d;
        lds[m * 65 + c + 2] = v.z * d;
        lds[m * 65 + c + 3] = v.w * d;
    }
    __syncthreads();
    size_t obase = (size_t)b * NN * CC + (size_t)kt * 2048;
    int kin = t & 31;
    int chi = t >> 5;
    #pragma unroll
    for (int cg = 0; cg < 8; ++cg) {
        int c = cg * 8 + chi;
        yph[obase + c * 32 + kin] = (unsigned short)bf16_rne(lds[kin * 65 + c]);
    }
}

// ---------------- K4: MFMA diffusion GEMM, async double-buffered LDS staging ----
// Block: 4 waves x 64n = 256 n; sweeps 512 m (one split) in 4 chunks of 128.
#define GMC 128
__global__ __launch_bounds__(256) void k_gemm(const ull* __restrict__ mask,
                                              const unsigned short* __restrict__ yph,
                                              float* __restrict__ plx) {
    __shared__ unsigned short ldsB[2][4 * 2048];   // 2 x 16 KB
    int t = threadIdx.x;
    int l = t & 63, wv = t >> 6;
    int lc = l & 15, q = l >> 4;
    int b = blockIdx.z;
    int ms = blockIdx.y;                  // m-split 0..7
    int n0 = blockIdx.x * 256 + wv * 64;
    int m0 = ms * 512;
    const unsigned short* src = yph + (size_t)b * NN * CC;

    // hoist all mask words for this wave's 512-m sweep (4 chunks x 2 words x 4 nt)
    ull mw[4][4][2];
    #pragma unroll
    for (int nt = 0; nt < 4; ++nt) {
        const ull* mrow = mask + ((size_t)(b * NN + n0 + nt * 16 + lc)) * NWRD + (m0 >> 6);
        #pragma unroll
        for (int mc = 0; mc < 4; ++mc) {
            mw[mc][nt][0] = mrow[mc * 2];
            mw[mc][nt][1] = mrow[mc * 2 + 1];
        }
    }

    f32x4 acc[4][4];
    #pragma unroll
    for (int nt = 0; nt < 4; ++nt)
        #pragma unroll
        for (int tt = 0; tt < 4; ++tt) acc[nt][tt] = f32x4{0.f, 0.f, 0.f, 0.f};

    auto stage = [&](int mc, int bufi) {
        int ktbase = (m0 + mc * GMC) >> 5;
        #pragma unroll
        for (int rd = 0; rd < 4; ++rd) {
            int gu = rd * 256 + wv * 64;              // wave-uniform part
            gload_lds16(src + (size_t)ktbase * 2048 + (gu + l) * 8, &ldsB[bufi][gu * 8]);
        }
    };

    stage(0, 0);
    for (int mc = 0; mc < 4; ++mc) {
        __syncthreads();
        if (mc + 1 < 4) stage(mc + 1, (mc + 1) & 1);
        int bufi = mc & 1;
        #pragma unroll
        for (int kt = 0; kt < 4; ++kt) {
            int sh = (kt & 1) * 32 + q * 8;
            union { unsigned int u[4]; short8 v; } a[4];
            #pragma unroll
            for (int nt = 0; nt < 4; ++nt) {
                unsigned int bits = (unsigned int)(mw[mc][nt][kt >> 1] >> sh) & 0xFFu;
                #pragma unroll
                for (int j = 0; j < 4; ++j)
                    a[nt].u[j] = ((bits >> (2 * j)) & 1u ? 0x3F80u : 0u)
                               | ((bits >> (2 * j + 1)) & 1u ? 0x3F800000u : 0u);
            }
            #pragma unroll
            for (int tt = 0; tt < 4; ++tt) {
                short8 bf = *(const short8*)&ldsB[bufi][kt * 2048 + (tt * 16 + lc) * 32 + q * 8];
                #pragma unroll
                for (int nt = 0; nt < 4; ++nt)
                    acc[nt][tt] = __builtin_amdgcn_mfma_f32_16x16x32_bf16(a[nt].v, bf, acc[nt][tt], 0, 0, 0);
            }
        }
    }
    #pragma unroll
    for (int nt = 0; nt < 4; ++nt)
        #pragma unroll
        for (int tt = 0; tt < 4; ++tt)
            #pragma unroll
            for (int r = 0; r < 4; ++r) {
                int n = n0 + nt * 16 + q * 4 + r;
                int c = tt * 16 + lc;
                plx[((size_t)((ms * BB + b)) * NN + n) * CC + c] = acc[nt][tt][r];
            }
}

// ---------------- K5: reduce partials, *dinv_n, @W, instance norm, relu ---------
// W column in VGPRs; lxs row via broadcast ds_read_b128.
__global__ __launch_bounds__(256) void k_out(const float* __restrict__ plx,
                                             const int* __restrict__ deg,
                                             const float* __restrict__ W,
                                             float* __restrict__ xout,
                                             unsigned short* __restrict__ xpack) {
    __shared__ float lxs[4][68];
    int lane = threadIdx.x & 63;
    int wave = threadIdx.x >> 6;
    int b = blockIdx.y;
    int n0 = blockIdx.x * 16 + wave * 4;
    float Wreg[64];                     // W[:, lane] — coalesced per c across lanes
    #pragma unroll
    for (int c = 0; c < 64; ++c) Wreg[c] = W[c * 64 + lane];
    for (int tI = 0; tI < 4; ++tI) {
        int n = n0 + tI;
        size_t row = (size_t)(b * NN + n);
        float dRow = rsqrtf((float)deg[row]);
        float lx = 0.f;
        #pragma unroll
        for (int s = 0; s < MSPLITS; ++s)
            lx += plx[((size_t)(s * BB + b) * NN + n) * CC + lane];
        lx *= dRow;
        lxs[wave][lane] = lx;            // same-wave LDS exchange (in-order DS)
        float h = 0.f;
        #pragma unroll
        for (int c4 = 0; c4 < 16; ++c4) {
            float4 s4 = *(const float4*)&lxs[wave][c4 * 4];   // broadcast b128
            h += s4.x * Wreg[c4 * 4 + 0] + s4.y * Wreg[c4 * 4 + 1]
               + s4.z * Wreg[c4 * 4 + 2] + s4.w * Wreg[c4 * 4 + 3];
        }
        float mean = h;
        #pragma unroll
        for (int off = 32; off; off >>= 1) mean += __shfl_xor(mean, off, 64);
        mean *= (1.f / 64.f);
        float dv = h - mean;
        float var = dv * dv;
        #pragma unroll
        for (int off = 32; off; off >>= 1) var += __shfl_xor(var, off, 64);
        var *= (1.f / 64.f);
        float o = dv * rsqrtf(var + EPSN);
        o = o > 0.f ? o : 0.f;
        if (xout)
            xout[row * CC + lane] = o;
        if (xpack)   // next-layer B: bf16(o * dinv_n)
            xpack[(size_t)b * NN * CC + (size_t)(n >> 5) * 2048 + lane * 32 + (n & 31)] =
                (unsigned short)bf16_rne(o * dRow);
    }
}

extern "C" void kernel_launch(void* const* d_in, const int* in_sizes, int n_in,
                              void* d_out, int out_size, void* d_ws, size_t ws_size,
                              hipStream_t stream) {
    const float* x  = (const float*)d_in[0];
    const float* W0 = (const float*)d_in[1];
    const float* W1 = (const float*)d_in[2];
    float* out = (float*)d_out;

    char* ws = (char*)d_ws;
    // Workspace layout (~52.1 MiB total)
    ull* mask = (ull*)(ws);                                           // 8 MiB
    float* xt = (float*)(ws + ((size_t)8 << 20));                     // 4 MiB
    unsigned short* ynh = (unsigned short*)(ws + ((size_t)12 << 20)); // 2 MiB
    unsigned short* ynl = (unsigned short*)(ws + ((size_t)14 << 20)); // 2 MiB
    unsigned short* xp0 = (unsigned short*)(ws + ((size_t)16 << 20)); // 2 MiB
    unsigned short* xp1 = (unsigned short*)(ws + ((size_t)18 << 20)); // 2 MiB
    float* plx = (float*)(ws + ((size_t)20 << 20));                   // 32 MiB
    int* deg = (int*)(ws + ((size_t)52 << 20));                       // 64 KiB

    // Build adjacency (deg zeroed in k_transpose, accumulated in k_corr)
    k_transpose<<<dim3(NN / 64, BB), 256, 0, stream>>>(x, xt, ynh, ynl, deg);
    k_corr<<<dim3(136, 1, BB), 256, 0, stream>>>(ynh, ynl, mask, deg);

    // Layer 1
    k_pack<<<dim3(128, BB), 256, 0, stream>>>(xt, deg, xp0);
    k_gemm<<<dim3(NN / 256, MSPLITS, BB), 256, 0, stream>>>(mask, xp0, plx);
    k_out<<<dim3(NN / 16, BB), 256, 0, stream>>>(plx, deg, W0, nullptr, xp1);

    // Layer 2
    k_gemm<<<dim3(NN / 256, MSPLITS, BB), 256, 0, stream>>>(mask, xp1, plx);
    k_out<<<dim3(NN / 16, BB), 256, 0, stream>>>(plx, deg, W1, out, nullptr);
}